// Round 10
// baseline (373.855 us; speedup 1.0000x reference)
//
#include <hip/hip_runtime.h>
#include <math.h>

#define NN 50000
#define NE 800000
#define HD 128
#define NL 3
#define NG 64
#define BN_EPS 1e-5f
#define SB 640   // stats slot: sum[128] | sumsq[128] | sc[128] | sh[128] | neg[128]
#define NB 196   // dst buckets of 256 nodes
#define EPB 4096 // edges per block in bucket passes
#define MAXB 8192
#define WSTR 136 // LDS weight row stride (fp16 elems)
#define AST 132  // LDS A-tile row stride (fp16 elems)

typedef _Float16 f16;
typedef __attribute__((ext_vector_type(8))) _Float16 f16x8;
typedef __attribute__((ext_vector_type(4))) float f32x4;

// ================= CSR build: bucketed counting sort =================
__global__ __launch_bounds__(256)
void buckcnt_kernel(const int* __restrict__ dst, int* __restrict__ bcnt) {
    __shared__ int h[NB];
    for (int i = threadIdx.x; i < NB; i += 256) h[i] = 0;
    __syncthreads();
    int base = blockIdx.x * EPB;
#pragma unroll
    for (int it = 0; it < EPB / 256; ++it) {
        int e = base + it * 256 + threadIdx.x;
        if (e < NE) atomicAdd(&h[dst[e] >> 8], 1);
    }
    __syncthreads();
    for (int i = threadIdx.x; i < NB; i += 256)
        if (h[i]) atomicAdd(&bcnt[i], h[i]);
}

__global__ void buckscan_kernel(const int* __restrict__ bcnt, int* __restrict__ bbase,
                                int* __restrict__ bcur) {
    __shared__ int sh[256];
    int tid = threadIdx.x;
    int v = (tid < NB) ? bcnt[tid] : 0;
    sh[tid] = v;
    __syncthreads();
    for (int off = 1; off < 256; off <<= 1) {
        int t = (tid >= off) ? sh[tid - off] : 0;
        __syncthreads();
        sh[tid] += t;
        __syncthreads();
    }
    int excl = sh[tid] - v;
    if (tid < NB) { bbase[tid] = excl; bcur[tid] = excl; }
    if (tid == NB - 1) bbase[NB] = excl + v;  // == NE
}

__global__ __launch_bounds__(256)
void buckscat_kernel(const int* __restrict__ src, const int* __restrict__ dst,
                     int* __restrict__ bcur, unsigned* __restrict__ staging) {
    __shared__ int h[NB];
    __shared__ int rbase[NB];
    for (int i = threadIdx.x; i < NB; i += 256) h[i] = 0;
    __syncthreads();
    int base = blockIdx.x * EPB;
#pragma unroll
    for (int it = 0; it < EPB / 256; ++it) {
        int e = base + it * 256 + threadIdx.x;
        if (e < NE) atomicAdd(&h[dst[e] >> 8], 1);
    }
    __syncthreads();
    for (int i = threadIdx.x; i < NB; i += 256) {
        rbase[i] = h[i] ? atomicAdd(&bcur[i], h[i]) : 0;
        h[i] = 0;
    }
    __syncthreads();
#pragma unroll
    for (int it = 0; it < EPB / 256; ++it) {
        int e = base + it * 256 + threadIdx.x;
        if (e < NE) {
            int d = dst[e];
            int k = d >> 8;
            int p = rbase[k] + atomicAdd(&h[k], 1);
            staging[p] = ((unsigned)d << 16) | (unsigned)src[e];
        }
    }
}

__global__ __launch_bounds__(256)
void buckbuild_kernel(const unsigned* __restrict__ staging, const int* __restrict__ bbase,
                      int* __restrict__ rowptr, int* __restrict__ perm) {
    __shared__ int cnt[256];
    __shared__ int pre[256];
    __shared__ unsigned short lperm[MAXB];
    const int k = blockIdx.x;
    const int s = bbase[k], e = bbase[k + 1];
    const int size = e - s;
    const int tid = threadIdx.x;
    cnt[tid] = 0;
    __syncthreads();
    for (int i = s + tid; i < e; i += 256)
        atomicAdd(&cnt[(int)(staging[i] >> 16) - k * 256], 1);
    __syncthreads();
    int v = cnt[tid];
    pre[tid] = v;
    __syncthreads();
    for (int off = 1; off < 256; off <<= 1) {
        int t = (tid >= off) ? pre[tid - off] : 0;
        __syncthreads();
        pre[tid] += t;
        __syncthreads();
    }
    int excl = pre[tid] - v;
    int n = k * 256 + tid;
    if (n < NN) rowptr[n] = s + excl;
    if (n == NN - 1) rowptr[NN] = NE;
    cnt[tid] = excl;  // reuse as scatter cursors
    __syncthreads();
    if (size <= MAXB) {
        for (int i = s + tid; i < e; i += 256) {
            unsigned w = staging[i];
            int dl = (int)(w >> 16) - k * 256;
            int p = atomicAdd(&cnt[dl], 1);
            lperm[p] = (unsigned short)(w & 0xffffu);
        }
        __syncthreads();
        for (int i = tid; i < size; i += 256) perm[s + i] = (int)lperm[i];
    } else {  // safety fallback (statistically unreachable)
        for (int i = s + tid; i < e; i += 256) {
            unsigned w = staging[i];
            int dl = (int)(w >> 16) - k * 256;
            int p = atomicAdd(&cnt[dl], 1);
            perm[s + p] = (int)(w & 0xffffu);
        }
    }
}

// ================= misc prep =================
__global__ void bounds_kernel(const int* __restrict__ batch, int* __restrict__ gb) {
    int n = blockIdx.x * 256 + threadIdx.x;
    if (n >= NN) return;
    int b = batch[n];
    int bp = (n == 0) ? -1 : batch[n - 1];
    for (int g = bp + 1; g <= b; ++g) gb[g] = n;
    if (n == NN - 1)
        for (int g = b + 1; g <= NG; ++g) gb[g] = NN;
}

__global__ void statsinit_kernel(float* __restrict__ stats0) {
    int c = threadIdx.x;  // 128
    stats0[256 + c] = 1.0f;  // sc
    stats0[384 + c] = 0.0f;  // sh
    stats0[512 + c] = 0.0f;  // neg = -sh/sc
}

__global__ void cvt_kernel(const float* __restrict__ x, f16* __restrict__ hf) {
    int t = blockIdx.x * 256 + threadIdx.x;
    if (t >= NN * 16) return;
    int n = t >> 4, q = t & 15;
    float4 v0 = ((const float4*)x)[n * 32 + q * 2];
    float4 v1 = ((const float4*)x)[n * 32 + q * 2 + 1];
    f16x8 o;
    o[0] = (f16)v0.x; o[1] = (f16)v0.y; o[2] = (f16)v0.z; o[3] = (f16)v0.w;
    o[4] = (f16)v1.x; o[5] = (f16)v1.y; o[6] = (f16)v1.z; o[7] = (f16)v1.w;
    *(f16x8*)(hf + (size_t)n * HD + q * 8) = o;
}

// ---- weight prep: Wh[j][k] = fp16(W[j][k]*scp[k]); bias2 = bl + shp@(Wl+Wr)^T ----
__global__ void wprep_kernel(const float* __restrict__ Wl, const float* __restrict__ Wr,
                             const float* __restrict__ bl, const float* __restrict__ statsP,
                             f16* __restrict__ Wh, float* __restrict__ bias2) {
    __shared__ float red[256];
    int j = blockIdx.x;   // 0..127 output channel
    int k = threadIdx.x;  // 0..255 contraction index
    float scp = statsP[256 + (k & 127)];
    float shp = statsP[384 + (k & 127)];
    float w = (k < HD) ? Wl[j * HD + k] : Wr[j * HD + (k - HD)];
    Wh[j * 256 + k] = (f16)(w * scp);
    red[k] = shp * w;
    __syncthreads();
    for (int s = 128; s > 0; s >>= 1) {
        if (k < s) red[k] += red[k + s];
        __syncthreads();
    }
    if (k == 0) bias2[j] = bl[j] + red[0];
}

// ================= fused layer: gather -> LDS A-tile -> fp16 MFMA GEMM =================
// y = relu([mean_nbr(hf) | hf] @ Wh^T + bias2), BN partial sums -> statsN.
// block = 256 thr = 4 waves, 64 nodes/block.
// Phase 1: gather 64 rows into LDS (16 lanes/node, fp32 accum, fp16 store —
//          identical rounding to the old aggf round-trip).
// Phase 2: 2 K-halves; W half staged to LDS; A-left from LDS, A-right from global.
// LDS: A 16.9KB + W 34.8KB + st 1KB = 52.7KB -> 3 blocks/CU.
__global__ __launch_bounds__(256, 3)
void layer_kernel(const f16* __restrict__ hf, const int* __restrict__ rowptr,
                  const int* __restrict__ perm, const float* __restrict__ statsP,
                  const f16* __restrict__ Wh, const float* __restrict__ bias2,
                  f16* __restrict__ yout, float* __restrict__ statsN) {
    __shared__ f16 als[64 * AST];     // gathered A-left tile
    __shared__ f16 wls[128 * WSTR];   // W half; aliased as f32 ls[64][132] in epilogue
    __shared__ float st[256];
    float* ls = (float*)wls;
    const int tid = threadIdx.x;
    st[tid] = 0.0f;

    // ---------- phase 1: gather ----------
    const int q = tid & 15;
#pragma unroll
    for (int p = 0; p < 4; ++p) {
        int nb = p * 16 + (tid >> 4);
        int n = blockIdx.x * 64 + nb;
        float sA[8] = {0.f, 0.f, 0.f, 0.f, 0.f, 0.f, 0.f, 0.f};
        float sB[8] = {0.f, 0.f, 0.f, 0.f, 0.f, 0.f, 0.f, 0.f};
        if (n < NN) {
            int r0 = rowptr[n], r1 = rowptr[n + 1];
            int e = r0;
            for (; e + 8 <= r1; e += 8) {
                int i0 = perm[e], i1 = perm[e + 1], i2 = perm[e + 2], i3 = perm[e + 3];
                int i4 = perm[e + 4], i5 = perm[e + 5], i6 = perm[e + 6], i7 = perm[e + 7];
                f16x8 v0 = *(const f16x8*)(hf + (size_t)i0 * HD + q * 8);
                f16x8 v1 = *(const f16x8*)(hf + (size_t)i1 * HD + q * 8);
                f16x8 v2 = *(const f16x8*)(hf + (size_t)i2 * HD + q * 8);
                f16x8 v3 = *(const f16x8*)(hf + (size_t)i3 * HD + q * 8);
                f16x8 v4 = *(const f16x8*)(hf + (size_t)i4 * HD + q * 8);
                f16x8 v5 = *(const f16x8*)(hf + (size_t)i5 * HD + q * 8);
                f16x8 v6 = *(const f16x8*)(hf + (size_t)i6 * HD + q * 8);
                f16x8 v7 = *(const f16x8*)(hf + (size_t)i7 * HD + q * 8);
#pragma unroll
                for (int j = 0; j < 8; ++j) {
                    sA[j] += ((float)v0[j] + (float)v2[j]) + ((float)v4[j] + (float)v6[j]);
                    sB[j] += ((float)v1[j] + (float)v3[j]) + ((float)v5[j] + (float)v7[j]);
                }
            }
            for (; e + 2 <= r1; e += 2) {
                int i0 = perm[e], i1 = perm[e + 1];
                f16x8 v0 = *(const f16x8*)(hf + (size_t)i0 * HD + q * 8);
                f16x8 v1 = *(const f16x8*)(hf + (size_t)i1 * HD + q * 8);
#pragma unroll
                for (int j = 0; j < 8; ++j) { sA[j] += (float)v0[j]; sB[j] += (float)v1[j]; }
            }
            if (e < r1) {
                int i0 = perm[e];
                f16x8 v0 = *(const f16x8*)(hf + (size_t)i0 * HD + q * 8);
#pragma unroll
                for (int j = 0; j < 8; ++j) sA[j] += (float)v0[j];
            }
            if (r1 > r0) {
                float r = 1.0f / (float)(r1 - r0);
#pragma unroll
                for (int j = 0; j < 8; ++j) sA[j] = (sA[j] + sB[j]) * r;
            } else {
                const float* neg = statsP + 512;  // -sh/sc: folded GEMM contribution = 0
#pragma unroll
                for (int j = 0; j < 8; ++j) sA[j] = neg[q * 8 + j];
            }
        }
        f16x8 o;
#pragma unroll
        for (int j = 0; j < 8; ++j) o[j] = (f16)sA[j];
        *(f16x8*)&als[nb * AST + q * 8] = o;
    }

    // ---------- phase 2: MFMA ----------
    const int wave = tid >> 6, lane = tid & 63;
    const int lm = lane & 15, quad = lane >> 4;
    const int m0 = blockIdx.x * 64 + wave * 16;
    int ar = m0 + lm;
    if (ar >= NN) ar = NN - 1;  // clamp global reads; rows zeroed in epilogue

    f32x4 acc[8];
#pragma unroll
    for (int t = 0; t < 8; ++t) acc[t] = (f32x4){0.f, 0.f, 0.f, 0.f};

#pragma unroll
    for (int half = 0; half < 2; ++half) {
        __syncthreads();
#pragma unroll
        for (int it = 0; it < 8; ++it) {
            int slot = tid + it * 256;            // 2048 slots of 16 B
            int r = slot >> 4, c = slot & 15;
            *(f16x8*)&wls[r * WSTR + c * 8] =
                *(const f16x8*)(Wh + (size_t)r * 256 + half * 128 + c * 8);
        }
        __syncthreads();
        f16x8 a[4];
#pragma unroll
        for (int c = 0; c < 4; ++c) {
            if (half == 0)
                a[c] = *(const f16x8*)&als[(wave * 16 + lm) * AST + c * 32 + quad * 8];
            else
                a[c] = *(const f16x8*)(hf + (size_t)ar * HD + c * 32 + quad * 8);
        }
#pragma unroll
        for (int c = 0; c < 4; ++c) {
#pragma unroll
            for (int t = 0; t < 8; ++t) {
                f16x8 b = *(const f16x8*)&wls[(t * 16 + lm) * WSTR + c * 32 + quad * 8];
                acc[t] = __builtin_amdgcn_mfma_f32_16x16x32_f16(a[c], b, acc[t], 0, 0, 0);
            }
        }
    }
    __syncthreads();  // W done; wls becomes f32 epilogue tile

    // ---------- epilogue: bias + relu + BN partials + fp16 writeback ----------
#pragma unroll
    for (int t = 0; t < 8; ++t) {
        int n = t * 16 + lm;
        float bs = bias2[n];
        float s = 0.f, sq = 0.f;
#pragma unroll
        for (int r = 0; r < 4; ++r) {
            int gr = m0 + quad * 4 + r;
            float y = fmaxf(acc[t][r] + bs, 0.f);
            if (gr >= NN) y = 0.f;
            ls[(wave * 16 + quad * 4 + r) * 132 + n] = y;
            s += y; sq += y * y;
        }
        s += __shfl_xor(s, 16); s += __shfl_xor(s, 32);
        sq += __shfl_xor(sq, 16); sq += __shfl_xor(sq, 32);
        if (quad == 0) { atomicAdd(&st[n], s); atomicAdd(&st[128 + n], sq); }
    }
    __syncthreads();
    atomicAdd(&statsN[tid], st[tid]);

#pragma unroll
    for (int it = 0; it < 4; ++it) {
        int slot = tid + it * 256;
        int r = slot >> 4, c = slot & 15;
        int g = blockIdx.x * 64 + r;
        if (g < NN) {
            const float* p = &ls[r * 132 + c * 8];
            f16x8 o;
#pragma unroll
            for (int j = 0; j < 8; ++j) o[j] = (f16)p[j];
            *(f16x8*)(yout + (size_t)g * HD + c * 8) = o;
        }
    }
}

// ---------------- BN prep ----------------
__global__ void bnprep_kernel(float* __restrict__ statsN, const float* __restrict__ gamma,
                              const float* __restrict__ beta) {
    int c = threadIdx.x;  // 128
    float invN = 1.0f / (float)NN;
    float mu = statsN[c] * invN;
    float var = statsN[128 + c] * invN - mu * mu;
    var = var < 0.f ? 0.f : var;
    float sc = rsqrtf(var + BN_EPS) * gamma[c];
    float sh = beta[c] - mu * sc;
    statsN[256 + c] = sc;
    statsN[384 + c] = sh;
    statsN[512 + c] = (sc != 0.f) ? (-sh / sc) : 0.f;
}

// ---------------- pooling ----------------
__global__ __launch_bounds__(256)
void pool2_kernel(const f16* __restrict__ hf, const int* __restrict__ gb,
                  float* __restrict__ pooled) {
    __shared__ float red[16 * 128];
    int g = blockIdx.x >> 3, sp = blockIdx.x & 7;
    int s = gb[g], e = gb[g + 1];
    int q = threadIdx.x & 15, r = threadIdx.x >> 4;
    float a[8] = {0.f, 0.f, 0.f, 0.f, 0.f, 0.f, 0.f, 0.f};
    for (int n = s + sp * 16 + r; n < e; n += 128) {
        f16x8 v = *(const f16x8*)(hf + (size_t)n * HD + q * 8);
#pragma unroll
        for (int j = 0; j < 8; ++j) a[j] += (float)v[j];
    }
#pragma unroll
    for (int j = 0; j < 8; ++j) red[r * 128 + q * 8 + j] = a[j];
    __syncthreads();
    for (int stp = 8; stp >= 1; stp >>= 1) {
        if (r < stp) {
#pragma unroll
            for (int j = 0; j < 8; ++j)
                red[r * 128 + q * 8 + j] += red[(r + stp) * 128 + q * 8 + j];
        }
        __syncthreads();
    }
    if (r == 0) {
#pragma unroll
        for (int j = 0; j < 8; ++j) atomicAdd(&pooled[g * HD + q * 8 + j], red[q * 8 + j]);
    }
}

// ---------------- head ----------------
__global__ void head_kernel(const float* __restrict__ pooled, const int* __restrict__ gb,
                            const float* __restrict__ stats3, const float* __restrict__ fcw,
                            const float* __restrict__ fcb, float* __restrict__ out) {
    __shared__ float red[2];
    int g = blockIdx.x, c = threadIdx.x;  // 128 threads
    float cnt = (float)(gb[g + 1] - gb[g]);
    float v = (pooled[g * HD + c] * stats3[256 + c] + cnt * stats3[384 + c]) * fcw[c];
#pragma unroll
    for (int o = 32; o > 0; o >>= 1) v += __shfl_xor(v, o);
    if ((c & 63) == 0) red[c >> 6] = v;
    __syncthreads();
    if (c == 0) {
        float s = red[0] + red[1] + fcb[0];
        out[g] = 1.0f / (1.0f + expf(-s));
    }
}

extern "C" void kernel_launch(void* const* d_in, const int* in_sizes, int n_in,
                              void* d_out, int out_size, void* d_ws, size_t ws_size,
                              hipStream_t stream) {
    const float* x     = (const float*)d_in[0];
    const int*   ei    = (const int*)d_in[1];
    const int*   src   = ei;
    const int*   dst   = ei + NE;
    const int*   batch = (const int*)d_in[3];
    const float* Wl    = (const float*)d_in[4];
    const float* bl    = (const float*)d_in[5];
    const float* Wr    = (const float*)d_in[6];
    const float* gamma = (const float*)d_in[7];
    const float* beta  = (const float*)d_in[8];
    const float* fcw   = (const float*)d_in[9];
    const float* fcb   = (const float*)d_in[10];
    float* out = (float*)d_out;

    f16* hf0  = (f16*)d_ws;                       // [NN][128] fp16 (x converted)
    f16* hfA  = hf0 + (size_t)NN * HD;
    f16* hfB  = hfA + (size_t)NN * HD;
    f16* Wh   = hfB + (size_t)NN * HD;            // [128][256] fp16
    float* bias2    = (float*)(Wh + 128 * 256);   // 128
    float* statsAll = bias2 + HD;                 // 4*SB
    float* pooled   = statsAll + 4 * SB;          // NG*HD
    int* rowptr  = (int*)(pooled + NG * HD);      // NN+1
    int* perm    = rowptr + NN + 1;               // NE
    unsigned* staging = (unsigned*)(perm + NE);   // NE
    int* bcnt    = (int*)(staging + NE);          // NB
    int* bbase   = bcnt + NB;                     // NB+1
    int* bcur    = bbase + NB + 1;                // NB
    int* gb      = bcur + NB;                     // NG+1

    hipMemsetAsync(bcnt, 0, NB * sizeof(int), stream);
    hipMemsetAsync(pooled, 0, NG * HD * sizeof(float), stream);
    hipMemsetAsync(statsAll, 0, 4 * SB * sizeof(float), stream);

    buckcnt_kernel<<<(NE + EPB - 1) / EPB, 256, 0, stream>>>(dst, bcnt);
    buckscan_kernel<<<1, 256, 0, stream>>>(bcnt, bbase, bcur);
    buckscat_kernel<<<(NE + EPB - 1) / EPB, 256, 0, stream>>>(src, dst, bcur, staging);
    buckbuild_kernel<<<NB, 256, 0, stream>>>(staging, bbase, rowptr, perm);
    bounds_kernel<<<(NN + 255) / 256, 256, 0, stream>>>(batch, gb);
    statsinit_kernel<<<1, 128, 0, stream>>>(statsAll);
    cvt_kernel<<<(NN * 16 + 255) / 256, 256, 0, stream>>>(x, hf0);

    const f16* hin = hf0;
    f16* houts[3] = {hfA, hfB, hfA};
    for (int l = 0; l < NL; ++l) {
        float* stP = statsAll + l * SB;
        float* stN = statsAll + (l + 1) * SB;
        wprep_kernel<<<128, 256, 0, stream>>>(Wl + l * HD * HD, Wr + l * HD * HD,
                                              bl + l * HD, stP, Wh, bias2);
        layer_kernel<<<(NN + 63) / 64, 256, 0, stream>>>(hin, rowptr, perm, stP, Wh,
                                                         bias2, houts[l], stN);
        bnprep_kernel<<<1, 128, 0, stream>>>(stN, gamma + l * HD, beta + l * HD);
        hin = houts[l];
    }
    pool2_kernel<<<NG * 8, 256, 0, stream>>>(hfA, gb, pooled);
    head_kernel<<<NG, 128, 0, stream>>>(pooled, gb, statsAll + 3 * SB, fcw, fcb, out);
}

// Round 11
// 363.011 us; speedup vs baseline: 1.0299x; 1.0299x over previous
//
#include <hip/hip_runtime.h>
#include <math.h>

#define NN 50000
#define NE 800000
#define HD 128
#define NL 3
#define NG 64
#define BN_EPS 1e-5f
#define SB 640   // stats slot: sum[128] | sumsq[128] | sc[128] | sh[128] | neg[128]
#define NB 196   // dst buckets of 256 nodes
#define EPB 4096 // edges per block in bucket passes
#define MAXB 8192
#define WSTR 136 // LDS weight row stride (fp16 elems)

typedef _Float16 f16;
typedef __attribute__((ext_vector_type(8))) _Float16 f16x8;
typedef __attribute__((ext_vector_type(4))) float f32x4;

// ================= CSR build: bucketed counting sort =================
__global__ __launch_bounds__(256)
void buckcnt_kernel(const int* __restrict__ dst, int* __restrict__ bcnt) {
    __shared__ int h[NB];
    for (int i = threadIdx.x; i < NB; i += 256) h[i] = 0;
    __syncthreads();
    int base = blockIdx.x * EPB;
#pragma unroll
    for (int it = 0; it < EPB / 256; ++it) {
        int e = base + it * 256 + threadIdx.x;
        if (e < NE) atomicAdd(&h[dst[e] >> 8], 1);
    }
    __syncthreads();
    for (int i = threadIdx.x; i < NB; i += 256)
        if (h[i]) atomicAdd(&bcnt[i], h[i]);
}

__global__ void buckscan_kernel(const int* __restrict__ bcnt, int* __restrict__ bbase,
                                int* __restrict__ bcur) {
    __shared__ int sh[256];
    int tid = threadIdx.x;
    int v = (tid < NB) ? bcnt[tid] : 0;
    sh[tid] = v;
    __syncthreads();
    for (int off = 1; off < 256; off <<= 1) {
        int t = (tid >= off) ? sh[tid - off] : 0;
        __syncthreads();
        sh[tid] += t;
        __syncthreads();
    }
    int excl = sh[tid] - v;
    if (tid < NB) { bbase[tid] = excl; bcur[tid] = excl; }
    if (tid == NB - 1) bbase[NB] = excl + v;  // == NE
}

__global__ __launch_bounds__(256)
void buckscat_kernel(const int* __restrict__ src, const int* __restrict__ dst,
                     int* __restrict__ bcur, unsigned* __restrict__ staging) {
    __shared__ int h[NB];
    __shared__ int rbase[NB];
    for (int i = threadIdx.x; i < NB; i += 256) h[i] = 0;
    __syncthreads();
    int base = blockIdx.x * EPB;
#pragma unroll
    for (int it = 0; it < EPB / 256; ++it) {
        int e = base + it * 256 + threadIdx.x;
        if (e < NE) atomicAdd(&h[dst[e] >> 8], 1);
    }
    __syncthreads();
    for (int i = threadIdx.x; i < NB; i += 256) {
        rbase[i] = h[i] ? atomicAdd(&bcur[i], h[i]) : 0;
        h[i] = 0;
    }
    __syncthreads();
#pragma unroll
    for (int it = 0; it < EPB / 256; ++it) {
        int e = base + it * 256 + threadIdx.x;
        if (e < NE) {
            int d = dst[e];
            int k = d >> 8;
            int p = rbase[k] + atomicAdd(&h[k], 1);
            staging[p] = ((unsigned)d << 16) | (unsigned)src[e];
        }
    }
}

__global__ __launch_bounds__(256)
void buckbuild_kernel(const unsigned* __restrict__ staging, const int* __restrict__ bbase,
                      int* __restrict__ rowptr, int* __restrict__ perm) {
    __shared__ int cnt[256];
    __shared__ int pre[256];
    __shared__ unsigned short lperm[MAXB];
    const int k = blockIdx.x;
    const int s = bbase[k], e = bbase[k + 1];
    const int size = e - s;
    const int tid = threadIdx.x;
    cnt[tid] = 0;
    __syncthreads();
    for (int i = s + tid; i < e; i += 256)
        atomicAdd(&cnt[(int)(staging[i] >> 16) - k * 256], 1);
    __syncthreads();
    int v = cnt[tid];
    pre[tid] = v;
    __syncthreads();
    for (int off = 1; off < 256; off <<= 1) {
        int t = (tid >= off) ? pre[tid - off] : 0;
        __syncthreads();
        pre[tid] += t;
        __syncthreads();
    }
    int excl = pre[tid] - v;
    int n = k * 256 + tid;
    if (n < NN) rowptr[n] = s + excl;
    if (n == NN - 1) rowptr[NN] = NE;
    cnt[tid] = excl;  // reuse as scatter cursors
    __syncthreads();
    if (size <= MAXB) {
        for (int i = s + tid; i < e; i += 256) {
            unsigned w = staging[i];
            int dl = (int)(w >> 16) - k * 256;
            int p = atomicAdd(&cnt[dl], 1);
            lperm[p] = (unsigned short)(w & 0xffffu);
        }
        __syncthreads();
        for (int i = tid; i < size; i += 256) perm[s + i] = (int)lperm[i];
    } else {  // safety fallback (statistically unreachable)
        for (int i = s + tid; i < e; i += 256) {
            unsigned w = staging[i];
            int dl = (int)(w >> 16) - k * 256;
            int p = atomicAdd(&cnt[dl], 1);
            perm[s + p] = (int)(w & 0xffffu);
        }
    }
}

// ================= misc prep =================
// bounds + stats-slot-0 identity init (fused: one less launch)
__global__ void bounds_kernel(const int* __restrict__ batch, int* __restrict__ gb,
                              float* __restrict__ stats0) {
    int n = blockIdx.x * 256 + threadIdx.x;
    if (blockIdx.x == 0 && threadIdx.x < 128) {
        stats0[256 + threadIdx.x] = 1.0f;  // sc
        stats0[384 + threadIdx.x] = 0.0f;  // sh
        stats0[512 + threadIdx.x] = 0.0f;  // neg = -sh/sc
    }
    if (n >= NN) return;
    int b = batch[n];
    int bp = (n == 0) ? -1 : batch[n - 1];
    for (int g = bp + 1; g <= b; ++g) gb[g] = n;
    if (n == NN - 1)
        for (int g = b + 1; g <= NG; ++g) gb[g] = NN;
}

__global__ void cvt_kernel(const float* __restrict__ x, f16* __restrict__ hf) {
    int t = blockIdx.x * 256 + threadIdx.x;
    if (t >= NN * 16) return;
    int n = t >> 4, q = t & 15;
    float4 v0 = ((const float4*)x)[n * 32 + q * 2];
    float4 v1 = ((const float4*)x)[n * 32 + q * 2 + 1];
    f16x8 o;
    o[0] = (f16)v0.x; o[1] = (f16)v0.y; o[2] = (f16)v0.z; o[3] = (f16)v0.w;
    o[4] = (f16)v1.x; o[5] = (f16)v1.y; o[6] = (f16)v1.z; o[7] = (f16)v1.w;
    *(f16x8*)(hf + (size_t)n * HD + q * 8) = o;
}

// ---- weight prep: Wh[j][k] = fp16(W[j][k]*scp[k]); bias2 = bl + shp@(Wl+Wr)^T ----
__global__ void wprep_kernel(const float* __restrict__ Wl, const float* __restrict__ Wr,
                             const float* __restrict__ bl, const float* __restrict__ statsP,
                             f16* __restrict__ Wh, float* __restrict__ bias2) {
    __shared__ float red[256];
    int j = blockIdx.x;   // 0..127 output channel
    int k = threadIdx.x;  // 0..255 contraction index
    float scp = statsP[256 + (k & 127)];
    float shp = statsP[384 + (k & 127)];
    float w = (k < HD) ? Wl[j * HD + k] : Wr[j * HD + (k - HD)];
    Wh[j * 256 + k] = (f16)(w * scp);
    red[k] = shp * w;
    __syncthreads();
    for (int s = 128; s > 0; s >>= 1) {
        if (k < s) red[k] += red[k + s];
        __syncthreads();
    }
    if (k == 0) bias2[j] = bl[j] + red[0];
}

// ---------------- gather: aggf[n] = fp16(mean over CSR row of hf[src]) ----------
// 16 lanes per node, 8 fp16 channels (16 B) per lane; fp32 accumulate.
// 16-edge batching: 16 independent 16B loads in flight per lane (latency-bound fix).
__global__ __launch_bounds__(256)
void gather_kernel(const f16* __restrict__ hf, const int* __restrict__ rowptr,
                   const int* __restrict__ perm, const float* __restrict__ statsP,
                   f16* __restrict__ aggf) {
    int t = blockIdx.x * 256 + threadIdx.x;
    int n = t >> 4, q = t & 15;
    if (n >= NN) return;
    int r0 = rowptr[n], r1 = rowptr[n + 1];
    float sA[8] = {0.f, 0.f, 0.f, 0.f, 0.f, 0.f, 0.f, 0.f};
    float sB[8] = {0.f, 0.f, 0.f, 0.f, 0.f, 0.f, 0.f, 0.f};
    int e = r0;
    for (; e + 16 <= r1; e += 16) {
        int ix[16];
#pragma unroll
        for (int j = 0; j < 16; ++j) ix[j] = perm[e + j];
        f16x8 v[16];
#pragma unroll
        for (int j = 0; j < 16; ++j)
            v[j] = *(const f16x8*)(hf + (size_t)ix[j] * HD + q * 8);
#pragma unroll
        for (int j = 0; j < 8; ++j) {
            sA[j] += (((float)v[0][j] + (float)v[2][j]) + ((float)v[4][j] + (float)v[6][j]))
                   + (((float)v[8][j] + (float)v[10][j]) + ((float)v[12][j] + (float)v[14][j]));
            sB[j] += (((float)v[1][j] + (float)v[3][j]) + ((float)v[5][j] + (float)v[7][j]))
                   + (((float)v[9][j] + (float)v[11][j]) + ((float)v[13][j] + (float)v[15][j]));
        }
    }
    for (; e + 8 <= r1; e += 8) {
        int i0 = perm[e], i1 = perm[e + 1], i2 = perm[e + 2], i3 = perm[e + 3];
        int i4 = perm[e + 4], i5 = perm[e + 5], i6 = perm[e + 6], i7 = perm[e + 7];
        f16x8 v0 = *(const f16x8*)(hf + (size_t)i0 * HD + q * 8);
        f16x8 v1 = *(const f16x8*)(hf + (size_t)i1 * HD + q * 8);
        f16x8 v2 = *(const f16x8*)(hf + (size_t)i2 * HD + q * 8);
        f16x8 v3 = *(const f16x8*)(hf + (size_t)i3 * HD + q * 8);
        f16x8 v4 = *(const f16x8*)(hf + (size_t)i4 * HD + q * 8);
        f16x8 v5 = *(const f16x8*)(hf + (size_t)i5 * HD + q * 8);
        f16x8 v6 = *(const f16x8*)(hf + (size_t)i6 * HD + q * 8);
        f16x8 v7 = *(const f16x8*)(hf + (size_t)i7 * HD + q * 8);
#pragma unroll
        for (int j = 0; j < 8; ++j) {
            sA[j] += ((float)v0[j] + (float)v2[j]) + ((float)v4[j] + (float)v6[j]);
            sB[j] += ((float)v1[j] + (float)v3[j]) + ((float)v5[j] + (float)v7[j]);
        }
    }
    for (; e + 2 <= r1; e += 2) {
        int i0 = perm[e], i1 = perm[e + 1];
        f16x8 v0 = *(const f16x8*)(hf + (size_t)i0 * HD + q * 8);
        f16x8 v1 = *(const f16x8*)(hf + (size_t)i1 * HD + q * 8);
#pragma unroll
        for (int j = 0; j < 8; ++j) { sA[j] += (float)v0[j]; sB[j] += (float)v1[j]; }
    }
    if (e < r1) {
        int i0 = perm[e];
        f16x8 v0 = *(const f16x8*)(hf + (size_t)i0 * HD + q * 8);
#pragma unroll
        for (int j = 0; j < 8; ++j) sA[j] += (float)v0[j];
    }
    float s[8];
#pragma unroll
    for (int j = 0; j < 8; ++j) s[j] = sA[j] + sB[j];
    if (r1 > r0) {
        float r = 1.0f / (float)(r1 - r0);
#pragma unroll
        for (int j = 0; j < 8; ++j) s[j] *= r;
    } else {
        const float* neg = statsP + 512;  // -sh/sc sentinel: BN-folded GEMM contribution = 0
#pragma unroll
        for (int j = 0; j < 8; ++j) s[j] = neg[q * 8 + j];
    }
    f16x8 o;
#pragma unroll
    for (int j = 0; j < 8; ++j) o[j] = (f16)s[j];
    *(f16x8*)(aggf + (size_t)n * HD + q * 8) = o;
}

// ---------------- fp16 MFMA GEMM, B staged in LDS, A hoisted ----------------
// y = relu([aggf | hf] @ Wh^T + bias2); all 8 A-fragment loads issued at kernel
// entry (in flight across W staging + first MFMA burst).
__global__ __launch_bounds__(256, 4)
void mfma_gemm(const f16* __restrict__ aggf, const f16* __restrict__ hf,
               const f16* __restrict__ Wh, const float* __restrict__ bias2,
               f16* __restrict__ yout, float* __restrict__ statsN) {
    __shared__ f16 wls[128 * WSTR];   // 34816 B; aliased as f32 ls[64][132] in epilogue
    __shared__ float st[256];
    float* ls = (float*)wls;
    const int tid = threadIdx.x;
    st[tid] = 0.0f;
    const int wave = tid >> 6, lane = tid & 63;
    const int lm = lane & 15, quad = lane >> 4;
    const int m0 = blockIdx.x * 64 + wave * 16;
    int ar = m0 + lm;
    if (ar >= NN) ar = NN - 1;  // clamp reads; invalid rows zeroed in epilogue

    // hoist ALL A-fragment loads (8 x 16B per lane) before any barrier
    f16x8 a[8];
#pragma unroll
    for (int c = 0; c < 4; ++c)
        a[c] = *(const f16x8*)(aggf + (size_t)ar * HD + c * 32 + quad * 8);
#pragma unroll
    for (int c = 0; c < 4; ++c)
        a[4 + c] = *(const f16x8*)(hf + (size_t)ar * HD + c * 32 + quad * 8);

    f32x4 acc[8];
#pragma unroll
    for (int t = 0; t < 8; ++t) acc[t] = (f32x4){0.f, 0.f, 0.f, 0.f};

#pragma unroll
    for (int half = 0; half < 2; ++half) {
        __syncthreads();
#pragma unroll
        for (int it = 0; it < 8; ++it) {
            int slot = tid + it * 256;            // 2048 slots of 16 B
            int r = slot >> 4, c = slot & 15;
            *(f16x8*)&wls[r * WSTR + c * 8] =
                *(const f16x8*)(Wh + (size_t)r * 256 + half * 128 + c * 8);
        }
        __syncthreads();
#pragma unroll
        for (int c = 0; c < 4; ++c) {
#pragma unroll
            for (int t = 0; t < 8; ++t) {
                f16x8 b = *(const f16x8*)&wls[(t * 16 + lm) * WSTR + c * 32 + quad * 8];
                acc[t] = __builtin_amdgcn_mfma_f32_16x16x32_f16(a[half * 4 + c], b, acc[t], 0, 0, 0);
            }
        }
    }
    __syncthreads();  // weights done; wls becomes f32 epilogue tile

#pragma unroll
    for (int t = 0; t < 8; ++t) {
        int n = t * 16 + lm;
        float bs = bias2[n];
        float s = 0.f, sq = 0.f;
#pragma unroll
        for (int r = 0; r < 4; ++r) {
            int gr = m0 + quad * 4 + r;
            float y = fmaxf(acc[t][r] + bs, 0.f);
            if (gr >= NN) y = 0.f;
            ls[(wave * 16 + quad * 4 + r) * 132 + n] = y;
            s += y; sq += y * y;
        }
        s += __shfl_xor(s, 16); s += __shfl_xor(s, 32);
        sq += __shfl_xor(sq, 16); sq += __shfl_xor(sq, 32);
        if (quad == 0) { atomicAdd(&st[n], s); atomicAdd(&st[128 + n], sq); }
    }
    __syncthreads();
    atomicAdd(&statsN[tid], st[tid]);

#pragma unroll
    for (int it = 0; it < 4; ++it) {
        int slot = tid + it * 256;
        int r = slot >> 4, c = slot & 15;
        int g = blockIdx.x * 64 + r;
        if (g < NN) {
            const float* p = &ls[r * 132 + c * 8];
            f16x8 o;
#pragma unroll
            for (int j = 0; j < 8; ++j) o[j] = (f16)p[j];
            *(f16x8*)(yout + (size_t)g * HD + c * 8) = o;
        }
    }
}

// ---------------- BN prep ----------------
__global__ void bnprep_kernel(float* __restrict__ statsN, const float* __restrict__ gamma,
                              const float* __restrict__ beta) {
    int c = threadIdx.x;  // 128
    float invN = 1.0f / (float)NN;
    float mu = statsN[c] * invN;
    float var = statsN[128 + c] * invN - mu * mu;
    var = var < 0.f ? 0.f : var;
    float sc = rsqrtf(var + BN_EPS) * gamma[c];
    float sh = beta[c] - mu * sc;
    statsN[256 + c] = sc;
    statsN[384 + c] = sh;
    statsN[512 + c] = (sc != 0.f) ? (-sh / sc) : 0.f;
}

// ---------------- pooling ----------------
__global__ __launch_bounds__(256)
void pool2_kernel(const f16* __restrict__ hf, const int* __restrict__ gb,
                  float* __restrict__ pooled) {
    __shared__ float red[16 * 128];
    int g = blockIdx.x >> 3, sp = blockIdx.x & 7;
    int s = gb[g], e = gb[g + 1];
    int q = threadIdx.x & 15, r = threadIdx.x >> 4;
    float a[8] = {0.f, 0.f, 0.f, 0.f, 0.f, 0.f, 0.f, 0.f};
    for (int n = s + sp * 16 + r; n < e; n += 128) {
        f16x8 v = *(const f16x8*)(hf + (size_t)n * HD + q * 8);
#pragma unroll
        for (int j = 0; j < 8; ++j) a[j] += (float)v[j];
    }
#pragma unroll
    for (int j = 0; j < 8; ++j) red[r * 128 + q * 8 + j] = a[j];
    __syncthreads();
    for (int stp = 8; stp >= 1; stp >>= 1) {
        if (r < stp) {
#pragma unroll
            for (int j = 0; j < 8; ++j)
                red[r * 128 + q * 8 + j] += red[(r + stp) * 128 + q * 8 + j];
        }
        __syncthreads();
    }
    if (r == 0) {
#pragma unroll
        for (int j = 0; j < 8; ++j) atomicAdd(&pooled[g * HD + q * 8 + j], red[q * 8 + j]);
    }
}

// ---------------- head ----------------
__global__ void head_kernel(const float* __restrict__ pooled, const int* __restrict__ gb,
                            const float* __restrict__ stats3, const float* __restrict__ fcw,
                            const float* __restrict__ fcb, float* __restrict__ out) {
    __shared__ float red[2];
    int g = blockIdx.x, c = threadIdx.x;  // 128 threads
    float cnt = (float)(gb[g + 1] - gb[g]);
    float v = (pooled[g * HD + c] * stats3[256 + c] + cnt * stats3[384 + c]) * fcw[c];
#pragma unroll
    for (int o = 32; o > 0; o >>= 1) v += __shfl_xor(v, o);
    if ((c & 63) == 0) red[c >> 6] = v;
    __syncthreads();
    if (c == 0) {
        float s = red[0] + red[1] + fcb[0];
        out[g] = 1.0f / (1.0f + expf(-s));
    }
}

extern "C" void kernel_launch(void* const* d_in, const int* in_sizes, int n_in,
                              void* d_out, int out_size, void* d_ws, size_t ws_size,
                              hipStream_t stream) {
    const float* x     = (const float*)d_in[0];
    const int*   ei    = (const int*)d_in[1];
    const int*   src   = ei;
    const int*   dst   = ei + NE;
    const int*   batch = (const int*)d_in[3];
    const float* Wl    = (const float*)d_in[4];
    const float* bl    = (const float*)d_in[5];
    const float* Wr    = (const float*)d_in[6];
    const float* gamma = (const float*)d_in[7];
    const float* beta  = (const float*)d_in[8];
    const float* fcw   = (const float*)d_in[9];
    const float* fcb   = (const float*)d_in[10];
    float* out = (float*)d_out;

    f16* hf0  = (f16*)d_ws;                       // [NN][128] fp16 (x converted)
    f16* hfA  = hf0 + (size_t)NN * HD;
    f16* hfB  = hfA + (size_t)NN * HD;
    f16* aggf = hfB + (size_t)NN * HD;
    f16* Wh   = aggf + (size_t)NN * HD;           // [128][256] fp16
    float* bias2    = (float*)(Wh + 128 * 256);   // 128
    float* statsAll = bias2 + HD;                 // 4*SB
    float* pooled   = statsAll + 4 * SB;          // NG*HD
    int* rowptr  = (int*)(pooled + NG * HD);      // NN+1
    int* perm    = rowptr + NN + 1;               // NE
    unsigned* staging = (unsigned*)(perm + NE);   // NE
    int* bcnt    = (int*)(staging + NE);          // NB
    int* bbase   = bcnt + NB;                     // NB+1
    int* bcur    = bbase + NB + 1;                // NB
    int* gb      = bcur + NB;                     // NG+1

    hipMemsetAsync(bcnt, 0, NB * sizeof(int), stream);
    hipMemsetAsync(pooled, 0, NG * HD * sizeof(float), stream);
    hipMemsetAsync(statsAll, 0, 4 * SB * sizeof(float), stream);

    buckcnt_kernel<<<(NE + EPB - 1) / EPB, 256, 0, stream>>>(dst, bcnt);
    buckscan_kernel<<<1, 256, 0, stream>>>(bcnt, bbase, bcur);
    buckscat_kernel<<<(NE + EPB - 1) / EPB, 256, 0, stream>>>(src, dst, bcur, staging);
    buckbuild_kernel<<<NB, 256, 0, stream>>>(staging, bbase, rowptr, perm);
    bounds_kernel<<<(NN + 255) / 256, 256, 0, stream>>>(batch, gb, statsAll);
    cvt_kernel<<<(NN * 16 + 255) / 256, 256, 0, stream>>>(x, hf0);

    const f16* hin = hf0;
    f16* houts[3] = {hfA, hfB, hfA};
    for (int l = 0; l < NL; ++l) {
        float* stP = statsAll + l * SB;
        float* stN = statsAll + (l + 1) * SB;
        wprep_kernel<<<128, 256, 0, stream>>>(Wl + l * HD * HD, Wr + l * HD * HD,
                                              bl + l * HD, stP, Wh, bias2);
        gather_kernel<<<(NN * 16 + 255) / 256, 256, 0, stream>>>(hin, rowptr, perm, stP, aggf);
        mfma_gemm<<<(NN + 63) / 64, 256, 0, stream>>>(aggf, hin, Wh, bias2, houts[l], stN);
        bnprep_kernel<<<1, 128, 0, stream>>>(stN, gamma + l * HD, beta + l * HD);
        hin = houts[l];
    }
    pool2_kernel<<<NG * 8, 256, 0, stream>>>(hfA, gb, pooled);
    head_kernel<<<NG, 128, 0, stream>>>(pooled, gb, statsAll + 3 * SB, fcw, fcb, out);
}